// Round 2
// baseline (30083.682 us; speedup 1.0000x reference)
//
#include <hip/hip_runtime.h>

#define Bsz 128
#define Lseq 512
#define Hdim 256
#define Tn 16
#define START_TAG 14
#define END_TAG 15

__device__ __forceinline__ float sigmoidf_(float x) {
    return 1.0f / (1.0f + __expf(-x));
}

__global__ void lengths_kernel(const int* __restrict__ tag, int* __restrict__ lengths) {
    int b = blockIdx.x;
    int tid = threadIdx.x;
    int cnt = 0;
    for (int l = tid; l < Lseq; l += blockDim.x)
        cnt += (tag[b * Lseq + l] != 0) ? 1 : 0;
    for (int off = 32; off > 0; off >>= 1) cnt += __shfl_down(cnt, off);
    __shared__ int red[4];
    if ((tid & 63) == 0) red[tid >> 6] = cnt;
    __syncthreads();
    if (tid == 0) lengths[b] = red[0] + red[1] + red[2] + red[3];
}

// Persistent BiLSTM. Grid = 256 WGs x 256 thr, 1 WG/CU (cooperative launch).
// WG id: dir (1b) | bg (1b, 64-batch half) | ug (6b, 4 hidden units).
// Per step: gate GEMM (64b x 16gc, k=512, weights L1-resident from global),
// cell update (c in VGPR), h -> global ping-pong, group barrier over the 64
// WGs sharing (dir,bg) via device-scope atomics, then this WG emits emission
// row b = bg*64+ug for its dir (h row read post-barrier).
__global__ __launch_bounds__(256) void bilstm_persist(
    const int* __restrict__ bd, const float* __restrict__ emb,
    const float* __restrict__ w_ih_f, const float* __restrict__ w_hh_f, const float* __restrict__ b_f,
    const float* __restrict__ w_ih_b, const float* __restrict__ w_hh_b, const float* __restrict__ b_b,
    const float* __restrict__ w_cls,
    float* __restrict__ em_f, float* __restrict__ em_b,
    float* __restrict__ hbuf,   // [dir][parity][B][H]
    int* __restrict__ ctr)      // [Lseq][4 groups]
{
    const int wg  = blockIdx.x;
    const int dir = wg >> 7;
    const int bg  = (wg >> 6) & 1;
    const int ug  = wg & 63;
    const int tid = threadIdx.x;
    const int grp = dir * 2 + bg;

    __shared__ float g_lds[64][17];
    __shared__ float part_lds[16][17];

    // ---- gate-GEMM identity: thread = (gc 0..15, bq 0..15), 4 batches each
    const int gc   = tid & 15;
    const int bq   = tid >> 4;
    const int gate = gc & 3;          // i,f,g,o
    const int u_l  = gc >> 2;         // 0..3
    const int grow = gate * 256 + ug * 4 + u_l;     // row in [4H, 256] weights
    const float* wihr = (dir ? w_ih_b : w_ih_f) + (size_t)grow * 256;
    const float* whhr = (dir ? w_hh_b : w_hh_f) + (size_t)grow * 256;
    const float  bias = (dir ? b_b : b_f)[grow];
    const int b0 = bg * 64 + bq * 4;  // 4 consecutive global batches

    // ---- cell identity: thread = (bl 0..63, ul 0..3)
    const int bl = tid >> 2;
    const int ul = tid & 3;
    const int cell_row = (bg * 64 + bl) * Hdim + ug * 4 + ul;
    float c_reg = 0.f;

    // ---- emission identity: thread = (ej 0..15, eks 0..15)
    const int brow = bg * 64 + ug;
    const int ej = tid & 15, eks = tid >> 4;
    const float* wcr = w_cls + (size_t)ej * (2 * Hdim) + dir * Hdim + eks * 16;
    float* emout = dir ? em_b : em_f;

    float* hbase = hbuf + (size_t)dir * 2 * Bsz * Hdim;

    for (int s = 0; s < Lseq; ++s) {
        const int t   = dir ? (Lseq - 1 - s) : s;
        const int par = s & 1;
        const float* hprev = hbase + (size_t)(par ^ 1) * Bsz * Hdim;
        float*       hcur  = hbase + (size_t)par * Bsz * Hdim;

        // ---------- gate GEMM ----------
        const float* x0 = emb + (size_t)bd[(b0 + 0) * Lseq + t] * 256;
        const float* x1 = emb + (size_t)bd[(b0 + 1) * Lseq + t] * 256;
        const float* x2 = emb + (size_t)bd[(b0 + 2) * Lseq + t] * 256;
        const float* x3 = emb + (size_t)bd[(b0 + 3) * Lseq + t] * 256;
        const float* h0 = hprev + (size_t)(b0 + 0) * 256;
        const float* h1 = hprev + (size_t)(b0 + 1) * 256;
        const float* h2 = hprev + (size_t)(b0 + 2) * 256;
        const float* h3 = hprev + (size_t)(b0 + 3) * 256;
        float a0 = bias, a1 = bias, a2 = bias, a3 = bias;
        #pragma unroll 4
        for (int k = 0; k < 256; k += 4) {
            float4 wi = *(const float4*)(wihr + k);
            float4 wh = *(const float4*)(whhr + k);
            float4 v;
            v = *(const float4*)(x0 + k); a0 += v.x*wi.x + v.y*wi.y + v.z*wi.z + v.w*wi.w;
            v = *(const float4*)(x1 + k); a1 += v.x*wi.x + v.y*wi.y + v.z*wi.z + v.w*wi.w;
            v = *(const float4*)(x2 + k); a2 += v.x*wi.x + v.y*wi.y + v.z*wi.z + v.w*wi.w;
            v = *(const float4*)(x3 + k); a3 += v.x*wi.x + v.y*wi.y + v.z*wi.z + v.w*wi.w;
            v = *(const float4*)(h0 + k); a0 += v.x*wh.x + v.y*wh.y + v.z*wh.z + v.w*wh.w;
            v = *(const float4*)(h1 + k); a1 += v.x*wh.x + v.y*wh.y + v.z*wh.z + v.w*wh.w;
            v = *(const float4*)(h2 + k); a2 += v.x*wh.x + v.y*wh.y + v.z*wh.z + v.w*wh.w;
            v = *(const float4*)(h3 + k); a3 += v.x*wh.x + v.y*wh.y + v.z*wh.z + v.w*wh.w;
        }
        g_lds[bq * 4 + 0][gc] = a0;
        g_lds[bq * 4 + 1][gc] = a1;
        g_lds[bq * 4 + 2][gc] = a2;
        g_lds[bq * 4 + 3][gc] = a3;
        __syncthreads();

        // ---------- cell update ----------
        {
            float gi = g_lds[bl][ul * 4 + 0];
            float gf = g_lds[bl][ul * 4 + 1];
            float gg = g_lds[bl][ul * 4 + 2];
            float go = g_lds[bl][ul * 4 + 3];
            float cn = sigmoidf_(gf) * c_reg + sigmoidf_(gi) * tanhf(gg);
            c_reg = cn;
            hcur[cell_row] = sigmoidf_(go) * tanhf(cn);
        }
        __syncthreads();   // all waves drain stores (compiler waitcnt before barrier)

        // ---------- group barrier (64 WGs sharing dir,bg) ----------
        if (tid == 0) {
            int* c = &ctr[s * 4 + grp];
            __hip_atomic_fetch_add(c, 1, __ATOMIC_RELEASE, __HIP_MEMORY_SCOPE_AGENT);
            while (__hip_atomic_load(c, __ATOMIC_RELAXED, __HIP_MEMORY_SCOPE_AGENT) < 64)
                __builtin_amdgcn_s_sleep(2);
        }
        __syncthreads();
        __threadfence();   // agent acquire: invalidate stale L1/L2 before reading peers' h

        // ---------- emission row (this WG's batch) ----------
        {
            const float* hrow = hcur + (size_t)brow * 256 + eks * 16;
            float p = 0.f;
            #pragma unroll
            for (int i = 0; i < 16; i += 4) {
                float4 hv = *(const float4*)(hrow + i);
                float4 wv = *(const float4*)(wcr + i);
                p += hv.x*wv.x + hv.y*wv.y + hv.z*wv.z + hv.w*wv.w;
            }
            part_lds[ej][eks] = p;
        }
        __syncthreads();
        if (tid < 16) {
            float ssum = 0.f;
            #pragma unroll
            for (int q = 0; q < 16; ++q) ssum += part_lds[tid][q];
            emout[((size_t)brow * Lseq + t) * Tn + tid] = ssum;
        }
        __syncthreads();
    }
}

__global__ void golden_kernel(const int* __restrict__ tag,
                              const float* __restrict__ em_f,
                              const float* __restrict__ em_b,
                              const float* __restrict__ b_cls,
                              const float* __restrict__ trans,
                              float* __restrict__ golden)
{
    int b = blockIdx.x;
    int tid = threadIdx.x;
    float s = 0.f;
    for (int l = tid; l < Lseq; l += blockDim.x) {
        int tg = tag[b * Lseq + l];
        if (tg != 0) {
            int prev = (l == 0) ? START_TAG : tag[b * Lseq + l - 1];
            size_t e = ((size_t)b * Lseq + l) * Tn + tg;
            s += em_f[e] + em_b[e] + b_cls[tg] + trans[prev * Tn + tg];
        }
    }
    for (int off = 32; off > 0; off >>= 1) s += __shfl_down(s, off);
    __shared__ float red[4];
    if ((tid & 63) == 0) red[tid >> 6] = s;
    __syncthreads();
    if (tid == 0) atomicAdd(golden, red[0] + red[1] + red[2] + red[3]);
}

__global__ void crf_forward_kernel(const float* __restrict__ em_f,
                                   const float* __restrict__ em_b,
                                   const float* __restrict__ b_cls,
                                   const float* __restrict__ trans,
                                   const int* __restrict__ lengths,
                                   float* __restrict__ allpath)
{
    int b = blockIdx.x;
    int lane = threadIdx.x;
    int j = lane & 15;
    float tcol[16];
    #pragma unroll
    for (int i = 0; i < 16; ++i) tcol[i] = trans[i * Tn + j];
    float bc = b_cls[j];
    size_t e0 = ((size_t)b * Lseq) * Tn + j;
    float alpha = em_f[e0] + em_b[e0] + bc + tcol[START_TAG];
    int len = lengths[b];
    for (int t = 1; t < Lseq; ++t) {
        float av[16];
        float m = -1e30f;
        #pragma unroll
        for (int i = 0; i < 16; ++i) {
            av[i] = __shfl(alpha, i) + tcol[i];
            m = fmaxf(m, av[i]);
        }
        float sum = 0.f;
        #pragma unroll
        for (int i = 0; i < 16; ++i) sum += __expf(av[i] - m);
        size_t e = ((size_t)b * Lseq + t) * Tn + j;
        float nv = em_f[e] + em_b[e] + bc + m + __logf(sum);
        alpha = (t < len) ? nv : alpha;
    }
    if (lane == END_TAG) atomicAdd(allpath, alpha);
}

__global__ void finalize_kernel(const float* __restrict__ scal, float* __restrict__ out) {
    out[0] = (scal[1] - scal[0]) / (float)Bsz;
}

extern "C" void kernel_launch(void* const* d_in, const int* in_sizes, int n_in,
                              void* d_out, int out_size, void* d_ws, size_t ws_size,
                              hipStream_t stream)
{
    (void)in_sizes; (void)n_in; (void)out_size; (void)ws_size;
    const int*   bd     = (const int*)d_in[0];
    const int*   tag    = (const int*)d_in[1];
    const float* emb    = (const float*)d_in[2];
    const float* w_ih_f = (const float*)d_in[3];
    const float* w_hh_f = (const float*)d_in[4];
    const float* b_f    = (const float*)d_in[5];
    const float* w_ih_b = (const float*)d_in[6];
    const float* w_hh_b = (const float*)d_in[7];
    const float* b_b    = (const float*)d_in[8];
    const float* w_cls  = (const float*)d_in[9];
    const float* b_cls  = (const float*)d_in[10];
    const float* trans  = (const float*)d_in[11];
    float* out = (float*)d_out;

    float* ws    = (float*)d_ws;
    float* em_f  = ws;                                   // 128*512*16
    float* em_b  = em_f + (size_t)Bsz * Lseq * Tn;       // 128*512*16
    float* hbuf  = em_b + (size_t)Bsz * Lseq * Tn;       // 2*2*128*256
    float* scal  = hbuf + 4 * (size_t)Bsz * Hdim;        // 8
    int*   ctr   = (int*)(scal + 8);                     // 512*4
    int*   lengths = (int*)(ctr + Lseq * 4);             // 128

    // zero hbuf + scal + ctr (emission is fully overwritten; lengths computed)
    size_t zbytes = (4 * (size_t)Bsz * Hdim + 8 + Lseq * 4) * sizeof(float);
    hipMemsetAsync(hbuf, 0, zbytes, stream);

    lengths_kernel<<<Bsz, 256, 0, stream>>>(tag, lengths);

    void* kargs[] = {
        (void*)&bd, (void*)&emb,
        (void*)&w_ih_f, (void*)&w_hh_f, (void*)&b_f,
        (void*)&w_ih_b, (void*)&w_hh_b, (void*)&b_b,
        (void*)&w_cls, (void*)&em_f, (void*)&em_b,
        (void*)&hbuf, (void*)&ctr
    };
    hipLaunchCooperativeKernel((const void*)bilstm_persist,
                               dim3(256), dim3(256), kargs, 0, stream);

    golden_kernel<<<Bsz, 256, 0, stream>>>(tag, em_f, em_b, b_cls, trans, scal);
    crf_forward_kernel<<<Bsz, 64, 0, stream>>>(em_f, em_b, b_cls, trans, lengths, scal + 1);
    finalize_kernel<<<1, 1, 0, stream>>>(scal, out);
}

// Round 3
// 17686.049 us; speedup vs baseline: 1.7010x; 1.7010x over previous
//
#include <hip/hip_runtime.h>

#define Bsz 128
#define Lseq 512
#define Hdim 256
#define Tn 16
#define START_TAG 14
#define END_TAG 15

__device__ __forceinline__ float sigmoidf_(float x) {
    return 1.0f / (1.0f + __expf(-x));
}

// w: [1024, 256] row-major -> wt: [256, 1024] (k-major: gate cols contiguous)
__global__ void transpose_w_kernel(const float* __restrict__ w, float* __restrict__ wt) {
    int k = blockIdx.x;            // 0..255
    for (int c = threadIdx.x; c < 1024; c += blockDim.x)
        wt[k * 1024 + c] = w[c * 256 + k];
}

__global__ void lengths_kernel(const int* __restrict__ tag, int* __restrict__ lengths) {
    int b = blockIdx.x;
    int tid = threadIdx.x;
    int cnt = 0;
    for (int l = tid; l < Lseq; l += blockDim.x)
        cnt += (tag[b * Lseq + l] != 0) ? 1 : 0;
    for (int off = 32; off > 0; off >>= 1) cnt += __shfl_down(cnt, off);
    __shared__ int red[4];
    if ((tid & 63) == 0) red[tid >> 6] = cnt;
    __syncthreads();
    if (tid == 0) lengths[b] = red[0] + red[1] + red[2] + red[3];
}

// Persistent BiLSTM, 512 WGs (2/CU). WG = dir(2) x bg(8: 16 batches) x ug(32: 8 units).
// Group = (dir,bg): 32 WGs exchange h each step via agent-scope relaxed atomics
// (sc1: coherent through Infinity Cache, no L2 invalidation -> weights stay L1/L2-hot).
// Barrier: padded per-(step,group) counter, relaxed arrive after __syncthreads'
// vmcnt(0) store drain; tid0 spins, peers sleep at s_barrier.
__global__ __launch_bounds__(256, 2) void bilstm_persist(
    const int* __restrict__ bd, const float* __restrict__ emb,
    const float* __restrict__ wiht, const float* __restrict__ whht,  // [2][256][1024]
    const float* __restrict__ b_f, const float* __restrict__ b_b,
    const float* __restrict__ w_cls,
    float* __restrict__ em_f, float* __restrict__ em_b,
    float* __restrict__ hbuf,   // [dir][parity][B][H]
    int* __restrict__ ctr)      // [Lseq][16 groups][16 pad]
{
    const int wg  = blockIdx.x;
    const int dir = wg >> 8;
    const int bg  = (wg >> 5) & 7;
    const int ug  = wg & 31;
    const int grp = dir * 8 + bg;
    const int tid = threadIdx.x;
    const int gb0 = bg * 16;

    __shared__ float h_lds[16][260];
    __shared__ float g_lds[2][16][36];
    __shared__ float hs_lds[256];
    __shared__ float part_lds[8][33];

    // gate-GEMM identity: kh (0: x*Wih, 1: h*Whh), bq 0..15 (batch), gcq 0..7 (col quad)
    const int kh   = tid >> 7;
    const int bq   = (tid >> 3) & 15;
    const int gcq  = tid & 7;
    const int gate = gcq >> 1;
    const int uq   = gcq & 1;
    const int colbase = gate * 256 + ug * 8 + uq * 4;
    const float* wt = (kh ? whht : wiht) + (size_t)dir * (256 * 1024) + colbase;

    // cell identity (tid < 128): cb 0..15 batch, cu 0..7 unit
    const int cb = tid >> 3;
    const int cu = tid & 7;
    const float* bias = dir ? b_b : b_f;
    float c_reg = 0.f;

    // emission identity: this WG emits 8 tags for batch bsel
    const int bsel = gb0 + (ug >> 1);
    const int jh   = ug & 1;
    const int ej   = tid >> 5;     // 0..7
    const int ekk  = tid & 31;     // 0..31
    const float* wcr = w_cls + (size_t)(jh * 8 + ej) * (2 * Hdim) + dir * Hdim + ekk * 8;
    float* emout = dir ? em_b : em_f;

    float* hbase = hbuf + (size_t)dir * 2 * Bsz * Hdim;

    for (int s = 0; s < Lseq; ++s) {
        const int t   = dir ? (Lseq - 1 - s) : s;
        const int par = s & 1;
        const float* hprev = hbase + (size_t)(par ^ 1) * Bsz * Hdim;
        float*       hcur  = hbase + (size_t)par * Bsz * Hdim;

        // ---- stage h_{t-1} for group's 16 batches (coherent sc1 loads) ----
        #pragma unroll 4
        for (int r = 0; r < 16; ++r)
            h_lds[r][tid] = __hip_atomic_load(hprev + (size_t)(gb0 + r) * Hdim + tid,
                                              __ATOMIC_RELAXED, __HIP_MEMORY_SCOPE_AGENT);
        __syncthreads();

        // ---- gate GEMM: acc[4 cols] for batch bq, k=256 half ----
        float4 acc = {0.f, 0.f, 0.f, 0.f};
        if (kh == 0) {
            const int tok = bd[(gb0 + bq) * Lseq + t];
            const float* ar = emb + (size_t)tok * 256;
            #pragma unroll 2
            for (int k = 0; k < 256; k += 4) {
                float4 av = *(const float4*)(ar + k);
                const float* wk = wt + (size_t)k * 1024;
                float4 w0 = *(const float4*)(wk);
                float4 w1 = *(const float4*)(wk + 1024);
                float4 w2 = *(const float4*)(wk + 2048);
                float4 w3 = *(const float4*)(wk + 3072);
                acc.x += av.x * w0.x + av.y * w1.x + av.z * w2.x + av.w * w3.x;
                acc.y += av.x * w0.y + av.y * w1.y + av.z * w2.y + av.w * w3.y;
                acc.z += av.x * w0.z + av.y * w1.z + av.z * w2.z + av.w * w3.z;
                acc.w += av.x * w0.w + av.y * w1.w + av.z * w2.w + av.w * w3.w;
            }
        } else {
            #pragma unroll 2
            for (int k = 0; k < 256; k += 4) {
                float4 av = *(const float4*)&h_lds[bq][k];
                const float* wk = wt + (size_t)k * 1024;
                float4 w0 = *(const float4*)(wk);
                float4 w1 = *(const float4*)(wk + 1024);
                float4 w2 = *(const float4*)(wk + 2048);
                float4 w3 = *(const float4*)(wk + 3072);
                acc.x += av.x * w0.x + av.y * w1.x + av.z * w2.x + av.w * w3.x;
                acc.y += av.x * w0.y + av.y * w1.y + av.z * w2.y + av.w * w3.y;
                acc.z += av.x * w0.z + av.y * w1.z + av.z * w2.z + av.w * w3.z;
                acc.w += av.x * w0.w + av.y * w1.w + av.z * w2.w + av.w * w3.w;
            }
        }
        *(float4*)&g_lds[kh][bq][gcq * 4] = acc;
        __syncthreads();

        // ---- cell update (128 threads) ----
        if (tid < 128) {
            float gi = g_lds[0][cb][cu]      + g_lds[1][cb][cu]      + bias[ug * 8 + cu];
            float gf = g_lds[0][cb][8 + cu]  + g_lds[1][cb][8 + cu]  + bias[256 + ug * 8 + cu];
            float gg = g_lds[0][cb][16 + cu] + g_lds[1][cb][16 + cu] + bias[512 + ug * 8 + cu];
            float go = g_lds[0][cb][24 + cu] + g_lds[1][cb][24 + cu] + bias[768 + ug * 8 + cu];
            float cn = sigmoidf_(gf) * c_reg + sigmoidf_(gi) * tanhf(gg);
            c_reg = cn;
            float hn = sigmoidf_(go) * tanhf(cn);
            __hip_atomic_store(hcur + (size_t)(gb0 + cb) * Hdim + ug * 8 + cu, hn,
                               __ATOMIC_RELAXED, __HIP_MEMORY_SCOPE_AGENT);
        }
        __syncthreads();   // emits s_waitcnt vmcnt(0): all waves' sc1 h stores are at L3

        // ---- group barrier: 32 WGs, padded counter, relaxed ops only ----
        if (tid == 0) {
            int* c = &ctr[(s * 16 + grp) * 16];
            __hip_atomic_fetch_add(c, 1, __ATOMIC_RELAXED, __HIP_MEMORY_SCOPE_AGENT);
            while (__hip_atomic_load(c, __ATOMIC_RELAXED, __HIP_MEMORY_SCOPE_AGENT) < 32)
                __builtin_amdgcn_s_sleep(1);
        }
        __syncthreads();

        // ---- emission: 8 tags of batch bsel from full h_t (coherent loads) ----
        hs_lds[tid] = __hip_atomic_load(hcur + (size_t)bsel * Hdim + tid,
                                        __ATOMIC_RELAXED, __HIP_MEMORY_SCOPE_AGENT);
        __syncthreads();
        {
            const float* hsr = &hs_lds[ekk * 8];
            float p = 0.f;
            #pragma unroll
            for (int i = 0; i < 8; ++i) p += hsr[i] * wcr[i];
            part_lds[ej][ekk] = p;
        }
        __syncthreads();
        if (tid < 8) {
            float ssum = 0.f;
            #pragma unroll
            for (int q = 0; q < 32; ++q) ssum += part_lds[tid][q];
            emout[((size_t)bsel * Lseq + t) * Tn + jh * 8 + tid] = ssum;
        }
        // next iter's first touch of part_lds/hs_lds is 2+ barriers away: safe
    }
}

__global__ void golden_kernel(const int* __restrict__ tag,
                              const float* __restrict__ em_f,
                              const float* __restrict__ em_b,
                              const float* __restrict__ b_cls,
                              const float* __restrict__ trans,
                              float* __restrict__ golden)
{
    int b = blockIdx.x;
    int tid = threadIdx.x;
    float s = 0.f;
    for (int l = tid; l < Lseq; l += blockDim.x) {
        int tg = tag[b * Lseq + l];
        if (tg != 0) {
            int prev = (l == 0) ? START_TAG : tag[b * Lseq + l - 1];
            size_t e = ((size_t)b * Lseq + l) * Tn + tg;
            s += em_f[e] + em_b[e] + b_cls[tg] + trans[prev * Tn + tg];
        }
    }
    for (int off = 32; off > 0; off >>= 1) s += __shfl_down(s, off);
    __shared__ float red[4];
    if ((tid & 63) == 0) red[tid >> 6] = s;
    __syncthreads();
    if (tid == 0) atomicAdd(golden, red[0] + red[1] + red[2] + red[3]);
}

__global__ void crf_forward_kernel(const float* __restrict__ em_f,
                                   const float* __restrict__ em_b,
                                   const float* __restrict__ b_cls,
                                   const float* __restrict__ trans,
                                   const int* __restrict__ lengths,
                                   float* __restrict__ allpath)
{
    int b = blockIdx.x;
    int lane = threadIdx.x;
    int j = lane & 15;
    float tcol[16];
    #pragma unroll
    for (int i = 0; i < 16; ++i) tcol[i] = trans[i * Tn + j];
    float bc = b_cls[j];
    size_t e0 = ((size_t)b * Lseq) * Tn + j;
    float alpha = em_f[e0] + em_b[e0] + bc + tcol[START_TAG];
    int len = lengths[b];
    for (int t = 1; t < Lseq; ++t) {
        float av[16];
        float m = -1e30f;
        #pragma unroll
        for (int i = 0; i < 16; ++i) {
            av[i] = __shfl(alpha, i) + tcol[i];
            m = fmaxf(m, av[i]);
        }
        float sum = 0.f;
        #pragma unroll
        for (int i = 0; i < 16; ++i) sum += __expf(av[i] - m);
        size_t e = ((size_t)b * Lseq + t) * Tn + j;
        float nv = em_f[e] + em_b[e] + bc + m + __logf(sum);
        alpha = (t < len) ? nv : alpha;
    }
    if (lane == END_TAG) atomicAdd(allpath, alpha);
}

__global__ void finalize_kernel(const float* __restrict__ scal, float* __restrict__ out) {
    out[0] = (scal[1] - scal[0]) / (float)Bsz;
}

extern "C" void kernel_launch(void* const* d_in, const int* in_sizes, int n_in,
                              void* d_out, int out_size, void* d_ws, size_t ws_size,
                              hipStream_t stream)
{
    (void)in_sizes; (void)n_in; (void)out_size; (void)ws_size;
    const int*   bd     = (const int*)d_in[0];
    const int*   tag    = (const int*)d_in[1];
    const float* emb    = (const float*)d_in[2];
    const float* w_ih_f = (const float*)d_in[3];
    const float* w_hh_f = (const float*)d_in[4];
    const float* b_f    = (const float*)d_in[5];
    const float* w_ih_b = (const float*)d_in[6];
    const float* w_hh_b = (const float*)d_in[7];
    const float* b_b    = (const float*)d_in[8];
    const float* w_cls  = (const float*)d_in[9];
    const float* b_cls  = (const float*)d_in[10];
    const float* trans  = (const float*)d_in[11];
    float* out = (float*)d_out;

    float* ws    = (float*)d_ws;
    float* em_f  = ws;                                   // 128*512*16
    float* em_b  = em_f + (size_t)Bsz * Lseq * Tn;       // 128*512*16
    float* hbuf  = em_b + (size_t)Bsz * Lseq * Tn;       // 2*2*128*256
    float* scal  = hbuf + 4 * (size_t)Bsz * Hdim;        // 8
    int*   ctr   = (int*)(scal + 8);                     // 512*16*16
    int*   lengths = (int*)(ctr + Lseq * 16 * 16);       // 128
    float* wiht  = (float*)(lengths + 128);              // 2 * 256*1024
    float* whht  = wiht + 2 * (size_t)256 * 1024;        // 2 * 256*1024

    // zero hbuf + scal + ctr (contiguous region)
    size_t zbytes = (4 * (size_t)Bsz * Hdim + 8 + (size_t)Lseq * 16 * 16) * sizeof(float);
    hipMemsetAsync(hbuf, 0, zbytes, stream);

    transpose_w_kernel<<<256, 256, 0, stream>>>(w_ih_f, wiht);
    transpose_w_kernel<<<256, 256, 0, stream>>>(w_ih_b, wiht + (size_t)256 * 1024);
    transpose_w_kernel<<<256, 256, 0, stream>>>(w_hh_f, whht);
    transpose_w_kernel<<<256, 256, 0, stream>>>(w_hh_b, whht + (size_t)256 * 1024);
    lengths_kernel<<<Bsz, 256, 0, stream>>>(tag, lengths);

    void* kargs[] = {
        (void*)&bd, (void*)&emb,
        (void*)&wiht, (void*)&whht,
        (void*)&b_f, (void*)&b_b,
        (void*)&w_cls, (void*)&em_f, (void*)&em_b,
        (void*)&hbuf, (void*)&ctr
    };
    hipLaunchCooperativeKernel((const void*)bilstm_persist,
                               dim3(512), dim3(256), kargs, 0, stream);

    golden_kernel<<<Bsz, 256, 0, stream>>>(tag, em_f, em_b, b_cls, trans, scal);
    crf_forward_kernel<<<Bsz, 64, 0, stream>>>(em_f, em_b, b_cls, trans, lengths, scal + 1);
    finalize_kernel<<<1, 1, 0, stream>>>(scal, out);
}

// Round 4
// 2842.534 us; speedup vs baseline: 10.5834x; 6.2219x over previous
//
#include <hip/hip_runtime.h>

#define Bsz 128
#define Lseq 512
#define Hdim 256
#define Tn 16
#define START_TAG 14
#define END_TAG 15

typedef float f32x4 __attribute__((ext_vector_type(4)));
typedef short s16x8 __attribute__((ext_vector_type(8)));

__device__ __forceinline__ unsigned short f2bf(float f) {
    unsigned int u = __builtin_bit_cast(unsigned int, f);
    u += 0x7fffu + ((u >> 16) & 1u);          // RNE
    return (unsigned short)(u >> 16);
}
__device__ __forceinline__ float bf2f(unsigned int bits16) {
    return __builtin_bit_cast(float, bits16 << 16);
}
__device__ __forceinline__ float sigmoidf_(float x) {
    return 1.0f / (1.0f + __expf(-x));
}

// emb fp32 [V*256] -> packed bf16 pairs [V*128]
__global__ void embprep_kernel(const float* __restrict__ emb,
                               unsigned int* __restrict__ embb, int n2) {
    int i = blockIdx.x * blockDim.x + threadIdx.x;
    int stride = gridDim.x * blockDim.x;
    for (; i < n2; i += stride)
        embb[i] = (unsigned int)f2bf(emb[2 * i]) | ((unsigned int)f2bf(emb[2 * i + 1]) << 16);
}

// wcat[dir][col(1024)][k(512) bf16] : k<256 = Wih[col][k], k>=256 = Whh[col][k-256]
__global__ void wprep_kernel(const float* __restrict__ wih_f, const float* __restrict__ whh_f,
                             const float* __restrict__ wih_b, const float* __restrict__ whh_b,
                             unsigned int* __restrict__ wcat) {
    int col = blockIdx.x;
    int dir = blockIdx.y;
    const float* wih = dir ? wih_b : wih_f;
    const float* whh = dir ? whh_b : whh_f;
    int q = threadIdx.x;                     // uint index 0..255 (512 bf16)
    float f0, f1;
    if (q < 128) { f0 = wih[col * 256 + 2 * q];       f1 = wih[col * 256 + 2 * q + 1]; }
    else         { int k = 2 * q - 256;
                   f0 = whh[col * 256 + k];           f1 = whh[col * 256 + k + 1]; }
    wcat[((size_t)dir * 1024 + col) * 256 + q] =
        (unsigned int)f2bf(f0) | ((unsigned int)f2bf(f1) << 16);
}

__global__ void lengths_kernel(const int* __restrict__ tag, int* __restrict__ lengths) {
    int b = blockIdx.x;
    int tid = threadIdx.x;
    int cnt = 0;
    for (int l = tid; l < Lseq; l += blockDim.x)
        cnt += (tag[b * Lseq + l] != 0) ? 1 : 0;
    for (int off = 32; off > 0; off >>= 1) cnt += __shfl_down(cnt, off);
    __shared__ int red[4];
    if ((tid & 63) == 0) red[tid >> 6] = cnt;
    __syncthreads();
    if (tid == 0) lengths[b] = red[0] + red[1] + red[2] + red[3];
}

// Persistent BiLSTM, 256 WGs (1/CU). WG = dir(2) x bg(8: 16 batches) x ug(16: 16 units).
// Weight slice (64 cols x 512 k, bf16) pinned in LDS -> zero weight traffic.
// Gate GEMM via mfma_f32_16x16x32_bf16 (wave w = gate w's 16 cols, k=512).
// h exchanged as packed bf16 via agent-scope relaxed atomics; flag-line barrier
// per (dir,bg) group of 16 WGs; x(t+1) prefetched during barrier wait.
__global__ __launch_bounds__(256, 1) void bilstm_persist(
    const int* __restrict__ bd,
    const unsigned int* __restrict__ embb,     // [V][128]
    const unsigned int* __restrict__ wcat,     // [2][1024][256]
    const float* __restrict__ b_f, const float* __restrict__ b_b,
    const float* __restrict__ w_cls,
    float* __restrict__ em_f, float* __restrict__ em_b,
    unsigned int* __restrict__ hbuf_u32,       // [2 dir][2 par][128][128]
    int* __restrict__ flags)                   // [512][16 grp][16 wg]
{
    const int wg  = blockIdx.x;
    const int dir = wg >> 7;
    const int bg  = (wg >> 4) & 7;
    const int ug  = wg & 15;
    const int grp = dir * 8 + bg;
    const int tid = threadIdx.x;
    const int gb0 = bg * 16;

    __shared__ unsigned int w_u32[64 * 260];   // [64 cols][256 k-uints + 4 pad]
    __shared__ unsigned int xh_u32[16 * 260];  // [16 b][x 0..127 | h 128..255 | pad]
    __shared__ float g_lds[4][16][17];
    __shared__ float part_lds[16][17];
    __shared__ float bias_lds[64];

    // ---- one-time: weight slice + bias into LDS ----
    for (int i = 0; i < 64; ++i) {
        int flat = tid + 256 * i;
        int lc = flat >> 8, q = flat & 255;
        int gc = (lc >> 4) * 256 + ug * 16 + (lc & 15);
        w_u32[lc * 260 + q] = wcat[((size_t)dir * 1024 + gc) * 256 + q];
    }
    if (tid < 64) {
        const float* bias = dir ? b_b : b_f;
        bias_lds[tid] = bias[(tid >> 4) * 256 + ug * 16 + (tid & 15)];
    }

    // mfma identities: wave wv -> gate wv (cols wv*16..wv*16+15)
    const int wv = tid >> 6;
    const int l  = tid & 63;
    const int n  = l & 15;
    const int kq = l >> 4;
    const unsigned int* wfrag = &w_u32[(wv * 16 + n) * 260 + kq * 4];
    const unsigned int* afrag = &xh_u32[n * 260 + kq * 4];

    // cell identity
    const int cb = tid >> 4, cu = tid & 15;
    float c_reg = 0.f;

    // emission identity (batch gb0+ug, this dir's half)
    const int ej = tid & 15, eseg = tid >> 4;
    const float* wcr = w_cls + (size_t)ej * (2 * Hdim) + dir * Hdim + eseg * 16;
    float* emout = dir ? em_b : em_f;

    unsigned int* hb = hbuf_u32 + (size_t)dir * 2 * 16384;

    // ---- pre-stage x for s=0 ----
    {
        const int t0 = dir ? (Lseq - 1) : 0;
        for (int i = 0; i < 8; ++i) {
            int idx = tid + 256 * i;
            int r = idx >> 7, q = idx & 127;
            int tok = bd[(gb0 + r) * Lseq + t0];
            xh_u32[r * 260 + q] = embb[(size_t)tok * 128 + q];
        }
    }

    for (int s = 0; s < Lseq; ++s) {
        const int t   = dir ? (Lseq - 1 - s) : s;
        const int par = s & 1;
        const unsigned int* hprev = hb + (par ^ 1) * 16384;
        unsigned int*       hcur  = hb + par * 16384;

        // ---- stage h_{t-1} (coherent bf16-packed loads) ----
        for (int i = 0; i < 8; ++i) {
            int idx = tid + 256 * i;
            int r = idx >> 7, q = idx & 127;
            unsigned int v = __hip_atomic_load(hprev + (gb0 + r) * 128 + q,
                                               __ATOMIC_RELAXED, __HIP_MEMORY_SCOPE_AGENT);
            xh_u32[r * 260 + 128 + q] = v;
        }
        __syncthreads();                                   // (b) xh + w ready

        // ---- emission partial for t_prev (h just staged = h_{t_prev}) ----
        if (s > 0) {
            const unsigned int* hrow = &xh_u32[ug * 260 + 128 + eseg * 8];
            float p = 0.f;
            #pragma unroll
            for (int q = 0; q < 8; ++q) {
                unsigned int v = hrow[q];
                p += bf2f(v & 0xffffu) * wcr[2 * q] + bf2f(v >> 16) * wcr[2 * q + 1];
            }
            part_lds[ej][eseg] = p;
        }

        // ---- gate GEMM: D[16b x 16c] over k=512 ----
        f32x4 acc = {0.f, 0.f, 0.f, 0.f};
        #pragma unroll
        for (int kc = 0; kc < 16; ++kc) {
            s16x8 a  = *(const s16x8*)(afrag + kc * 16);
            s16x8 bb = *(const s16x8*)(wfrag + kc * 16);
            acc = __builtin_amdgcn_mfma_f32_16x16x32_bf16(a, bb, acc, 0, 0, 0);
        }
        #pragma unroll
        for (int r = 0; r < 4; ++r)
            g_lds[wv][kq * 4 + r][n] = acc[r];             // row=batch, col=unit
        __syncthreads();                                   // (c) g + part ready

        // ---- emission final ----
        if (s > 0 && tid < 16) {
            float ssum = 0.f;
            #pragma unroll
            for (int q2 = 0; q2 < 16; ++q2) ssum += part_lds[tid][q2];
            int t_prev = dir ? (Lseq - s) : (s - 1);
            emout[((size_t)(gb0 + ug) * Lseq + t_prev) * Tn + tid] = ssum;
        }

        // ---- cell update + packed bf16 h store ----
        {
            float gi = g_lds[0][cb][cu] + bias_lds[cu];
            float gf = g_lds[1][cb][cu] + bias_lds[16 + cu];
            float gg = g_lds[2][cb][cu] + bias_lds[32 + cu];
            float go = g_lds[3][cb][cu] + bias_lds[48 + cu];
            float cn = sigmoidf_(gf) * c_reg + sigmoidf_(gi) * tanhf(gg);
            c_reg = cn;
            float hn = sigmoidf_(go) * tanhf(cn);
            unsigned int hbits = (unsigned int)f2bf(hn);
            unsigned int other = (unsigned int)__shfl_down((int)hbits, 1);
            if ((cu & 1) == 0) {
                unsigned int pk = hbits | (other << 16);
                __hip_atomic_store(hcur + (gb0 + cb) * 128 + ug * 8 + (cu >> 1), pk,
                                   __ATOMIC_RELAXED, __HIP_MEMORY_SCOPE_AGENT);
            }
        }
        __syncthreads();                                   // (d) all h stores drained

        // ---- arrive (one flag per WG; group shares one 64B line) ----
        if (tid == 0)
            __hip_atomic_store(&flags[((size_t)s * 16 + grp) * 16 + ug], 1,
                               __ATOMIC_RELAXED, __HIP_MEMORY_SCOPE_AGENT);

        // ---- prefetch x(t+1) while waiting (no cross-WG dependency) ----
        if (s + 1 < Lseq) {
            const int tn = dir ? (Lseq - 2 - s) : (s + 1);
            for (int i = 0; i < 8; ++i) {
                int idx = tid + 256 * i;
                int r = idx >> 7, q = idx & 127;
                int tok = bd[(gb0 + r) * Lseq + tn];
                xh_u32[r * 260 + q] = embb[(size_t)tok * 128 + q];
            }
        }

        // ---- poll: wave0 lanes 0..15 watch the 16 flags (one line) ----
        if (wv == 0) {
            const int* flg = &flags[((size_t)s * 16 + grp) * 16];
            while (true) {
                int v = (l < 16)
                    ? __hip_atomic_load(&flg[l], __ATOMIC_RELAXED, __HIP_MEMORY_SCOPE_AGENT)
                    : 1;
                if (__all(v != 0)) break;
                __builtin_amdgcn_s_sleep(1);
            }
        }
        __syncthreads();                                   // (e) release whole WG
    }

    // ---- tail: emission for the final timestep's h ----
    {
        const int par = Lseq & 1;                          // 0
        const unsigned int* hprev = hb + (par ^ 1) * 16384;
        for (int i = 0; i < 8; ++i) {
            int idx = tid + 256 * i;
            int r = idx >> 7, q = idx & 127;
            unsigned int v = __hip_atomic_load(hprev + (gb0 + r) * 128 + q,
                                               __ATOMIC_RELAXED, __HIP_MEMORY_SCOPE_AGENT);
            xh_u32[r * 260 + 128 + q] = v;
        }
        __syncthreads();
        {
            const unsigned int* hrow = &xh_u32[ug * 260 + 128 + eseg * 8];
            float p = 0.f;
            #pragma unroll
            for (int q = 0; q < 8; ++q) {
                unsigned int v = hrow[q];
                p += bf2f(v & 0xffffu) * wcr[2 * q] + bf2f(v >> 16) * wcr[2 * q + 1];
            }
            part_lds[ej][eseg] = p;
        }
        __syncthreads();
        if (tid < 16) {
            float ssum = 0.f;
            #pragma unroll
            for (int q2 = 0; q2 < 16; ++q2) ssum += part_lds[tid][q2];
            int t_prev = dir ? 0 : (Lseq - 1);
            emout[((size_t)(gb0 + ug) * Lseq + t_prev) * Tn + tid] = ssum;
        }
    }
}

__global__ void golden_kernel(const int* __restrict__ tag,
                              const float* __restrict__ em_f,
                              const float* __restrict__ em_b,
                              const float* __restrict__ b_cls,
                              const float* __restrict__ trans,
                              float* __restrict__ golden)
{
    int b = blockIdx.x;
    int tid = threadIdx.x;
    float s = 0.f;
    for (int l = tid; l < Lseq; l += blockDim.x) {
        int tg = tag[b * Lseq + l];
        if (tg != 0) {
            int prev = (l == 0) ? START_TAG : tag[b * Lseq + l - 1];
            size_t e = ((size_t)b * Lseq + l) * Tn + tg;
            s += em_f[e] + em_b[e] + b_cls[tg] + trans[prev * Tn + tg];
        }
    }
    for (int off = 32; off > 0; off >>= 1) s += __shfl_down(s, off);
    __shared__ float red[4];
    if ((tid & 63) == 0) red[tid >> 6] = s;
    __syncthreads();
    if (tid == 0) atomicAdd(golden, red[0] + red[1] + red[2] + red[3]);
}

__global__ void crf_forward_kernel(const float* __restrict__ em_f,
                                   const float* __restrict__ em_b,
                                   const float* __restrict__ b_cls,
                                   const float* __restrict__ trans,
                                   const int* __restrict__ lengths,
                                   float* __restrict__ allpath)
{
    int b = blockIdx.x;
    int lane = threadIdx.x;
    int j = lane & 15;
    float tcol[16];
    #pragma unroll
    for (int i = 0; i < 16; ++i) tcol[i] = trans[i * Tn + j];
    float bc = b_cls[j];
    size_t e0 = ((size_t)b * Lseq) * Tn + j;
    float alpha = em_f[e0] + em_b[e0] + bc + tcol[START_TAG];
    int len = lengths[b];
    for (int t = 1; t < Lseq; ++t) {
        float av[16];
        float m = -1e30f;
        #pragma unroll
        for (int i = 0; i < 16; ++i) {
            av[i] = __shfl(alpha, i) + tcol[i];
            m = fmaxf(m, av[i]);
        }
        float sum = 0.f;
        #pragma unroll
        for (int i = 0; i < 16; ++i) sum += __expf(av[i] - m);
        size_t e = ((size_t)b * Lseq + t) * Tn + j;
        float nv = em_f[e] + em_b[e] + bc + m + __logf(sum);
        alpha = (t < len) ? nv : alpha;
    }
    if (lane == END_TAG) atomicAdd(allpath, alpha);
}

__global__ void finalize_kernel(const float* __restrict__ scal, float* __restrict__ out) {
    out[0] = (scal[1] - scal[0]) / (float)Bsz;
}

extern "C" void kernel_launch(void* const* d_in, const int* in_sizes, int n_in,
                              void* d_out, int out_size, void* d_ws, size_t ws_size,
                              hipStream_t stream)
{
    (void)in_sizes; (void)n_in; (void)out_size; (void)ws_size;
    const int*   bd     = (const int*)d_in[0];
    const int*   tag    = (const int*)d_in[1];
    const float* emb    = (const float*)d_in[2];
    const float* w_ih_f = (const float*)d_in[3];
    const float* w_hh_f = (const float*)d_in[4];
    const float* b_f    = (const float*)d_in[5];
    const float* w_ih_b = (const float*)d_in[6];
    const float* w_hh_b = (const float*)d_in[7];
    const float* b_b    = (const float*)d_in[8];
    const float* w_cls  = (const float*)d_in[9];
    const float* b_cls  = (const float*)d_in[10];
    const float* trans  = (const float*)d_in[11];
    float* out = (float*)d_out;

    float* ws = (float*)d_ws;
    float* em_f = ws;                                        // 1048576 f
    float* em_b = em_f + (size_t)Bsz * Lseq * Tn;            // 1048576 f
    unsigned int* hbuf = (unsigned int*)(em_b + (size_t)Bsz * Lseq * Tn);  // 65536 u
    float* scal = (float*)(hbuf + 65536);                    // 8 f
    int* flags = (int*)(scal + 8);                           // 512*16*16
    int* lengths = flags + (size_t)Lseq * 16 * 16;           // 128
    unsigned int* wcat = (unsigned int*)(lengths + 128);     // 2*1024*256
    unsigned int* embb = wcat + (size_t)2 * 1024 * 256;      // 30000*128

    // zero hbuf + scal + flags (contiguous)
    size_t zbytes = (65536 + 8 + (size_t)Lseq * 16 * 16) * 4;
    hipMemsetAsync(hbuf, 0, zbytes, stream);

    embprep_kernel<<<2048, 256, 0, stream>>>(emb, embb, 30000 * 128);
    wprep_kernel<<<dim3(1024, 2), 256, 0, stream>>>(w_ih_f, w_hh_f, w_ih_b, w_hh_b, wcat);
    lengths_kernel<<<Bsz, 256, 0, stream>>>(tag, lengths);

    void* kargs[] = {
        (void*)&bd, (void*)&embb, (void*)&wcat,
        (void*)&b_f, (void*)&b_b, (void*)&w_cls,
        (void*)&em_f, (void*)&em_b,
        (void*)&hbuf, (void*)&flags
    };
    hipLaunchCooperativeKernel((const void*)bilstm_persist,
                               dim3(256), dim3(256), kargs, 0, stream);

    golden_kernel<<<Bsz, 256, 0, stream>>>(tag, em_f, em_b, b_cls, trans, scal);
    crf_forward_kernel<<<Bsz, 64, 0, stream>>>(em_f, em_b, b_cls, trans, lengths, scal + 1);
    finalize_kernel<<<1, 1, 0, stream>>>(scal, out);
}

// Round 5
// 2348.306 us; speedup vs baseline: 12.8108x; 1.2105x over previous
//
#include <hip/hip_runtime.h>

#define Bsz 128
#define Lseq 512
#define Hdim 256
#define Tn 16
#define START_TAG 14
#define END_TAG 15

typedef float f32x4 __attribute__((ext_vector_type(4)));
typedef short s16x8 __attribute__((ext_vector_type(8)));

__device__ __forceinline__ unsigned short f2bf(float f) {
    unsigned int u = __builtin_bit_cast(unsigned int, f);
    u += 0x7fffu + ((u >> 16) & 1u);          // RNE
    return (unsigned short)(u >> 16);
}
__device__ __forceinline__ float bf2f(unsigned int bits16) {
    return __builtin_bit_cast(float, bits16 << 16);
}
__device__ __forceinline__ float sigmoidf_(float x) {
    return 1.0f / (1.0f + __expf(-x));
}

// emb fp32 [V*256] -> packed bf16 pairs [V*128]
__global__ void embprep_kernel(const float* __restrict__ emb,
                               unsigned int* __restrict__ embb, int n2) {
    int i = blockIdx.x * blockDim.x + threadIdx.x;
    int stride = gridDim.x * blockDim.x;
    for (; i < n2; i += stride)
        embb[i] = (unsigned int)f2bf(emb[2 * i]) | ((unsigned int)f2bf(emb[2 * i + 1]) << 16);
}

// wtile[dir][ug(16)][tl=gate(4)][ki(16)][lane(64)][4 uints] : MFMA B-frag order.
// lane l: n=l&15, kq=l>>4; uint j holds k-elems ki*32+kq*8+2j, +1 of col tl*256+ug*16+n.
__global__ void wprep_kernel(const float* __restrict__ wih_f, const float* __restrict__ whh_f,
                             const float* __restrict__ wih_b, const float* __restrict__ whh_b,
                             unsigned int* __restrict__ wtile) {
    int bid = blockIdx.x;                 // ((dir*16+ug)*4+tl)*16+ki
    int ki  = bid & 15;
    int tl  = (bid >> 4) & 3;
    int ug  = (bid >> 6) & 15;
    int dir = bid >> 10;
    int t = threadIdx.x;                  // 256 = lane(64) x j(4)
    int lane = t >> 2, j = t & 3;
    int n = lane & 15, kq = lane >> 4;
    int k0 = ki * 32 + kq * 8 + 2 * j;
    int col = tl * 256 + ug * 16 + n;
    const float* wih = dir ? wih_b : wih_f;
    const float* whh = dir ? whh_b : whh_f;
    float f0, f1;
    if (k0 < 256) { f0 = wih[col * 256 + k0];       f1 = wih[col * 256 + k0 + 1]; }
    else          { f0 = whh[col * 256 + k0 - 256]; f1 = whh[col * 256 + k0 - 255]; }
    wtile[(size_t)bid * 256 + t] = (unsigned int)f2bf(f0) | ((unsigned int)f2bf(f1) << 16);
}

__global__ void lengths_kernel(const int* __restrict__ tag, int* __restrict__ lengths) {
    int b = blockIdx.x;
    int tid = threadIdx.x;
    int cnt = 0;
    for (int l = tid; l < Lseq; l += blockDim.x)
        cnt += (tag[b * Lseq + l] != 0) ? 1 : 0;
    for (int off = 32; off > 0; off >>= 1) cnt += __shfl_down(cnt, off);
    __shared__ int red[4];
    if ((tid & 63) == 0) red[tid >> 6] = cnt;
    __syncthreads();
    if (tid == 0) lengths[b] = red[0] + red[1] + red[2] + red[3];
}

// Persistent BiLSTM, 256 WGs (1/CU). WG = dir(2) x bg(8: 16 batches) x ug(16: 16 units).
// Per step critical path: stage h (sc1) -> 8 h-MFMAs -> cell -> drain -> flag -> poll.
// x-half (8 MFMAs from register fragments) computed for s+1 during the poll window.
// Emission (tag j=ug for the 16 batches) piggybacks on the staged h. 2-slot h ring.
__global__ __launch_bounds__(256, 1) void bilstm_persist(
    const int* __restrict__ bd,
    const unsigned int* __restrict__ embb,     // [V][128]
    const unsigned int* __restrict__ wtile,    // frag-ordered weights
    const float* __restrict__ b_f, const float* __restrict__ b_b,
    const float* __restrict__ w_cls,
    float* __restrict__ em_f, float* __restrict__ em_b,
    unsigned int* __restrict__ ring,           // [2 dir][2 par][128 b][128 uints]
    int* __restrict__ flags)                   // [512][16 grp][16 wg]
{
    const int wg  = blockIdx.x;
    const int dir = wg >> 7;
    const int bg  = (wg >> 4) & 7;
    const int ug  = wg & 15;
    const int grp = dir * 8 + bg;
    const int tid = threadIdx.x;
    const int gb0 = bg * 16;

    __shared__ unsigned int w_lds[16384];      // [4 tl][16 ki][64 lane][4]
    __shared__ unsigned int h_lds[16 * 132];   // [16 m][128 uints + 4 pad]
    __shared__ float g_lds[4][16][17];
    __shared__ float part_lds[16][17];
    __shared__ float bias_lds[64];
    __shared__ float wcls_lds[256];

    // ---- one-time staging ----
    {
        const unsigned int* wsrc = wtile + ((size_t)(dir * 16 + ug) << 14);
        for (int i = 0; i < 16; ++i) {
            int idx = tid + 256 * i;
            uint4 v = *(const uint4*)(wsrc + (size_t)idx * 4);
            *(uint4*)&w_lds[idx * 4] = v;
        }
        if (tid < 64) {
            const float* bias = dir ? b_b : b_f;
            bias_lds[tid] = bias[(tid >> 4) * 256 + ug * 16 + (tid & 15)];
        }
        wcls_lds[tid] = w_cls[(size_t)ug * (2 * Hdim) + dir * Hdim + tid];
    }

    // identities
    const int wv = tid >> 6;        // wave = gate
    const int l  = tid & 63;
    const int n  = l & 15;          // col-in-tile / batch m for A
    const int kq = l >> 4;
    const int cb = tid >> 4, cu = tid & 15;            // cell: (batch, unit)
    const int em_m = tid >> 4, em_seg = tid & 15;      // emission partial
    float c_reg = 0.f;
    float* emout = dir ? em_b : em_f;
    const int* bd_row = bd + (size_t)(gb0 + n) * Lseq; // token row for A-frag rows

    unsigned int* rbase = ring + (size_t)dir * 2 * 16384;

    __syncthreads();   // w_lds/bias/wcls ready

    // ---- prologue: acc_x for s=0 ----
    f32x4 acc_x = {0.f, 0.f, 0.f, 0.f};
    {
        const int t0 = dir ? (Lseq - 1) : 0;
        int tok = bd_row[t0];
        const unsigned int* xsrc = embb + (size_t)tok * 128 + kq * 4;
        #pragma unroll
        for (int ki = 0; ki < 8; ++ki) {
            uint4 xv = *(const uint4*)(xsrc + ki * 16);
            s16x8 a = __builtin_bit_cast(s16x8, xv);
            s16x8 b = *(const s16x8*)&w_lds[((wv * 16 + ki) * 64 + l) * 4];
            acc_x = __builtin_amdgcn_mfma_f32_16x16x32_bf16(a, b, acc_x, 0, 0, 0);
        }
    }

    for (int s = 0; s < Lseq; ++s) {
        const int t = dir ? (Lseq - 1 - s) : s;
        const unsigned int* hprev = rbase + ((s & 1) ^ 1) * 16384;
        unsigned int*       hcur  = rbase + (s & 1) * 16384;

        // ---- A: stage h_{s-1} (sc1 dword loads -> LDS) ----
        {
            int m = tid >> 4, q0 = (tid & 15) * 8;
            const unsigned int* src = hprev + (gb0 + m) * 128 + q0;
            unsigned int v[8];
            #pragma unroll
            for (int j = 0; j < 8; ++j)
                v[j] = __hip_atomic_load(src + j, __ATOMIC_RELAXED, __HIP_MEMORY_SCOPE_AGENT);
            *(uint4*)&h_lds[m * 132 + q0]     = make_uint4(v[0], v[1], v[2], v[3]);
            *(uint4*)&h_lds[m * 132 + q0 + 4] = make_uint4(v[4], v[5], v[6], v[7]);
        }
        __syncthreads();

        // ---- B: emission partial (tag ug, h_{t_prev}) + 8 h-MFMAs ----
        if (s > 0) {
            const unsigned int* hr = &h_lds[em_m * 132 + em_seg * 8];
            const float* wc = &wcls_lds[em_seg * 16];
            float p = 0.f;
            #pragma unroll
            for (int j = 0; j < 8; ++j) {
                unsigned int v = hr[j];
                p += bf2f(v & 0xffffu) * wc[2 * j] + bf2f(v >> 16) * wc[2 * j + 1];
            }
            part_lds[em_m][em_seg] = p;
        }
        {
            f32x4 acc = acc_x;
            #pragma unroll
            for (int kih = 0; kih < 8; ++kih) {
                s16x8 a = *(const s16x8*)&h_lds[n * 132 + kih * 16 + kq * 4];
                s16x8 b = *(const s16x8*)&w_lds[(((wv * 16) + 8 + kih) * 64 + l) * 4];
                acc = __builtin_amdgcn_mfma_f32_16x16x32_bf16(a, b, acc, 0, 0, 0);
            }
            #pragma unroll
            for (int r = 0; r < 4; ++r)
                g_lds[wv][kq * 4 + r][n] = acc[r];
        }
        __syncthreads();

        // ---- C: cell update + packed h store; emission final ----
        {
            float gi = g_lds[0][cb][cu] + bias_lds[cu];
            float gf = g_lds[1][cb][cu] + bias_lds[16 + cu];
            float gg = g_lds[2][cb][cu] + bias_lds[32 + cu];
            float go = g_lds[3][cb][cu] + bias_lds[48 + cu];
            float cn = sigmoidf_(gf) * c_reg + sigmoidf_(gi) * tanhf(gg);
            c_reg = cn;
            float hn = sigmoidf_(go) * tanhf(cn);
            unsigned int hbits = (unsigned int)f2bf(hn);
            unsigned int other = (unsigned int)__shfl_down((int)hbits, 1);
            if ((cu & 1) == 0) {
                unsigned int pk = hbits | (other << 16);
                __hip_atomic_store(hcur + (gb0 + cb) * 128 + ug * 8 + (cu >> 1), pk,
                                   __ATOMIC_RELAXED, __HIP_MEMORY_SCOPE_AGENT);
            }
        }
        if (s > 0 && tid < 16) {
            float ssum = 0.f;
            #pragma unroll
            for (int q = 0; q < 16; ++q) ssum += part_lds[tid][q];
            int t_prev = dir ? (Lseq - s) : (s - 1);
            emout[((size_t)(gb0 + tid) * Lseq + t_prev) * Tn + ug] = ssum;
        }
        __syncthreads();   // drains h stores (vmcnt(0) before s_barrier)

        // ---- D: arrive ----
        if (tid == 0)
            __hip_atomic_store(&flags[((size_t)s * 16 + grp) * 16 + ug], 1,
                               __ATOMIC_RELAXED, __HIP_MEMORY_SCOPE_AGENT);

        // ---- E: x-half MFMAs for s+1 (register frags; hidden in poll window) ----
        if (s + 1 < Lseq) {
            const int tn = dir ? (Lseq - 2 - s) : (s + 1);
            int tok = bd_row[tn];
            const unsigned int* xsrc = embb + (size_t)tok * 128 + kq * 4;
            f32x4 ax = {0.f, 0.f, 0.f, 0.f};
            #pragma unroll
            for (int ki = 0; ki < 8; ++ki) {
                uint4 xv = *(const uint4*)(xsrc + ki * 16);
                s16x8 a = __builtin_bit_cast(s16x8, xv);
                s16x8 b = *(const s16x8*)&w_lds[((wv * 16 + ki) * 64 + l) * 4];
                ax = __builtin_amdgcn_mfma_f32_16x16x32_bf16(a, b, ax, 0, 0, 0);
            }
            acc_x = ax;
        }

        // ---- F: wave0 polls the 16 group flags (one cache line) ----
        if (wv == 0) {
            const int* flg = &flags[((size_t)s * 16 + grp) * 16];
            while (true) {
                int v = (l < 16)
                    ? __hip_atomic_load(&flg[l], __ATOMIC_RELAXED, __HIP_MEMORY_SCOPE_AGENT)
                    : 1;
                if (__all(v != 0)) break;
                __builtin_amdgcn_s_sleep(1);
            }
        }
        __syncthreads();
    }

    // ---- tail: emission for the last timestep's h ----
    {
        const unsigned int* hlast = rbase + ((Lseq - 1) & 1) * 16384;
        int m = tid >> 4, q0 = (tid & 15) * 8;
        const unsigned int* src = hlast + (gb0 + m) * 128 + q0;
        unsigned int v[8];
        #pragma unroll
        for (int j = 0; j < 8; ++j)
            v[j] = __hip_atomic_load(src + j, __ATOMIC_RELAXED, __HIP_MEMORY_SCOPE_AGENT);
        *(uint4*)&h_lds[m * 132 + q0]     = make_uint4(v[0], v[1], v[2], v[3]);
        *(uint4*)&h_lds[m * 132 + q0 + 4] = make_uint4(v[4], v[5], v[6], v[7]);
        __syncthreads();
        {
            const unsigned int* hr = &h_lds[em_m * 132 + em_seg * 8];
            const float* wc = &wcls_lds[em_seg * 16];
            float p = 0.f;
            #pragma unroll
            for (int j = 0; j < 8; ++j) {
                unsigned int vv = hr[j];
                p += bf2f(vv & 0xffffu) * wc[2 * j] + bf2f(vv >> 16) * wc[2 * j + 1];
            }
            part_lds[em_m][em_seg] = p;
        }
        __syncthreads();
        if (tid < 16) {
            float ssum = 0.f;
            #pragma unroll
            for (int q = 0; q < 16; ++q) ssum += part_lds[tid][q];
            int t_tail = dir ? 0 : (Lseq - 1);
            emout[((size_t)(gb0 + tid) * Lseq + t_tail) * Tn + ug] = ssum;
        }
    }
}

__global__ void golden_kernel(const int* __restrict__ tag,
                              const float* __restrict__ em_f,
                              const float* __restrict__ em_b,
                              const float* __restrict__ b_cls,
                              const float* __restrict__ trans,
                              float* __restrict__ golden)
{
    int b = blockIdx.x;
    int tid = threadIdx.x;
    float s = 0.f;
    for (int l = tid; l < Lseq; l += blockDim.x) {
        int tg = tag[b * Lseq + l];
        if (tg != 0) {
            int prev = (l == 0) ? START_TAG : tag[b * Lseq + l - 1];
            size_t e = ((size_t)b * Lseq + l) * Tn + tg;
            s += em_f[e] + em_b[e] + b_cls[tg] + trans[prev * Tn + tg];
        }
    }
    for (int off = 32; off > 0; off >>= 1) s += __shfl_down(s, off);
    __shared__ float red[4];
    if ((tid & 63) == 0) red[tid >> 6] = s;
    __syncthreads();
    if (tid == 0) atomicAdd(golden, red[0] + red[1] + red[2] + red[3]);
}

__global__ void crf_forward_kernel(const float* __restrict__ em_f,
                                   const float* __restrict__ em_b,
                                   const float* __restrict__ b_cls,
                                   const float* __restrict__ trans,
                                   const int* __restrict__ lengths,
                                   float* __restrict__ allpath)
{
    int b = blockIdx.x;
    int lane = threadIdx.x;
    int j = lane & 15;
    float tcol[16];
    #pragma unroll
    for (int i = 0; i < 16; ++i) tcol[i] = trans[i * Tn + j];
    float bc = b_cls[j];
    size_t e0 = ((size_t)b * Lseq) * Tn + j;
    float alpha = em_f[e0] + em_b[e0] + bc + tcol[START_TAG];
    int len = lengths[b];
    for (int t = 1; t < Lseq; ++t) {
        float av[16];
        float m = -1e30f;
        #pragma unroll
        for (int i = 0; i < 16; ++i) {
            av[i] = __shfl(alpha, i) + tcol[i];
            m = fmaxf(m, av[i]);
        }
        float sum = 0.f;
        #pragma unroll
        for (int i = 0; i < 16; ++i) sum += __expf(av[i] - m);
        size_t e = ((size_t)b * Lseq + t) * Tn + j;
        float nv = em_f[e] + em_b[e] + bc + m + __logf(sum);
        alpha = (t < len) ? nv : alpha;
    }
    if (lane == END_TAG) atomicAdd(allpath, alpha);
}

__global__ void finalize_kernel(const float* __restrict__ scal, float* __restrict__ out) {
    out[0] = (scal[1] - scal[0]) / (float)Bsz;
}

extern "C" void kernel_launch(void* const* d_in, const int* in_sizes, int n_in,
                              void* d_out, int out_size, void* d_ws, size_t ws_size,
                              hipStream_t stream)
{
    (void)in_sizes; (void)n_in; (void)out_size; (void)ws_size;
    const int*   bd     = (const int*)d_in[0];
    const int*   tag    = (const int*)d_in[1];
    const float* emb    = (const float*)d_in[2];
    const float* w_ih_f = (const float*)d_in[3];
    const float* w_hh_f = (const float*)d_in[4];
    const float* b_f    = (const float*)d_in[5];
    const float* w_ih_b = (const float*)d_in[6];
    const float* w_hh_b = (const float*)d_in[7];
    const float* b_b    = (const float*)d_in[8];
    const float* w_cls  = (const float*)d_in[9];
    const float* b_cls  = (const float*)d_in[10];
    const float* trans  = (const float*)d_in[11];
    float* out = (float*)d_out;

    float* ws = (float*)d_ws;
    float* em_f = ws;                                        // 1048576 f
    float* em_b = em_f + (size_t)Bsz * Lseq * Tn;            // 1048576 f
    unsigned int* ring = (unsigned int*)(em_b + (size_t)Bsz * Lseq * Tn);  // 65536 u
    float* scal = (float*)(ring + 65536);                    // 8 f
    int* flags = (int*)(scal + 8);                           // 512*16*16
    int* lengths = flags + (size_t)Lseq * 16 * 16;           // 128
    unsigned int* wtile = (unsigned int*)(lengths + 128);    // 2*16*4*16*256 = 524288
    unsigned int* embb = wtile + (size_t)524288;             // 30000*128

    // zero ring + scal + flags (contiguous)
    size_t zbytes = (65536 + 8 + (size_t)Lseq * 16 * 16) * 4;
    hipMemsetAsync(ring, 0, zbytes, stream);

    embprep_kernel<<<2048, 256, 0, stream>>>(emb, embb, 30000 * 128);
    wprep_kernel<<<2048, 256, 0, stream>>>(w_ih_f, w_hh_f, w_ih_b, w_hh_b, wtile);
    lengths_kernel<<<Bsz, 256, 0, stream>>>(tag, lengths);

    void* kargs[] = {
        (void*)&bd, (void*)&embb, (void*)&wtile,
        (void*)&b_f, (void*)&b_b, (void*)&w_cls,
        (void*)&em_f, (void*)&em_b,
        (void*)&ring, (void*)&flags
    };
    hipLaunchCooperativeKernel((const void*)bilstm_persist,
                               dim3(256), dim3(256), kargs, 0, stream);

    golden_kernel<<<Bsz, 256, 0, stream>>>(tag, em_f, em_b, b_cls, trans, scal);
    crf_forward_kernel<<<Bsz, 64, 0, stream>>>(em_f, em_b, b_cls, trans, lengths, scal + 1);
    finalize_kernel<<<1, 1, 0, stream>>>(scal, out);
}